// Round 1
// baseline (139.954 us; speedup 1.0000x reference)
//
#include <hip/hip_runtime.h>
#include <hip/hip_bf16.h>
#include <stdint.h>

#define BATCH 16384
#define NF 768
#define FT 1024

__device__ __forceinline__ float b2f(unsigned short u) {
    union { uint32_t i; float f; } x; x.i = ((uint32_t)u) << 16; return x.f;
}

// Kernel 1: W_ft [FT, NF] fp32 -> Wt [NF, FT] bf16 (transposed, round-to-nearest)
__global__ __launch_bounds__(256) void prep_wt(const float* __restrict__ W_ft,
                                               unsigned short* __restrict__ Wt) {
    int n = blockIdx.x * blockDim.x + threadIdx.x;  // n over NF*FT, o fastest
    if (n >= NF * FT) return;
    int o = n & (FT - 1);
    int f = n >> 10;
    float w = W_ft[(size_t)o * NF + f];
    __hip_bfloat16 h = __float2bfloat16(w);
    Wt[n] = *reinterpret_cast<unsigned short*>(&h);
}

// Kernel 2: fused sparse feature-transformer + SCReLU + output layer + sigmoid.
// One block per batch row; 256 threads; thread t owns outputs [4t, 4t+4) for
// both perspectives.
__global__ __launch_bounds__(256) void nnue_fwd(
    const float* __restrict__ bstm, const float* __restrict__ bnstm,
    const unsigned short* __restrict__ Wt, const float* __restrict__ b_ft,
    const float* __restrict__ W_out, const float* __restrict__ b_out,
    float* __restrict__ out)
{
    const int b = blockIdx.x;
    const int t = threadIdx.x;

    __shared__ int cnt[2];
    __shared__ int   fidx[2][NF];
    __shared__ float fval[2][NF];
    __shared__ float red[4];

    if (t < 2) cnt[t] = 0;
    __syncthreads();

    // Phase 1: compact nonzero features of both boards into LDS.
    // 192 threads x float4 covers 768 floats per perspective.
    if (t < 192) {
        const float4 vs = ((const float4*)(bstm  + (size_t)b * NF))[t];
        const float4 vn = ((const float4*)(bnstm + (size_t)b * NF))[t];
        const float v[2][4] = {{vs.x, vs.y, vs.z, vs.w}, {vn.x, vn.y, vn.z, vn.w}};
        #pragma unroll
        for (int p = 0; p < 2; ++p) {
            #pragma unroll
            for (int c = 0; c < 4; ++c) {
                if (v[p][c] != 0.0f) {
                    int slot = atomicAdd(&cnt[p], 1);
                    fidx[p][slot] = t * 4 + c;
                    fval[p][slot] = v[p][c];
                }
            }
        }
    }
    __syncthreads();

    // Phase 2: accumulate active W_T rows. Coalesced ushort4 (8B) loads of
    // bf16 weights; LDS index reads are wave-uniform broadcasts (free).
    float acc[2][4] = {};
    #pragma unroll
    for (int p = 0; p < 2; ++p) {
        const int n = cnt[p];
        const int base = t * 4;
        #pragma unroll 4
        for (int i = 0; i < n; ++i) {
            const int f = fidx[p][i];
            const float v = fval[p][i];
            const ushort4 w = *(const ushort4*)(Wt + (size_t)f * FT + base);
            acc[p][0] = fmaf(v, b2f(w.x), acc[p][0]);
            acc[p][1] = fmaf(v, b2f(w.y), acc[p][1]);
            acc[p][2] = fmaf(v, b2f(w.z), acc[p][2]);
            acc[p][3] = fmaf(v, b2f(w.w), acc[p][3]);
        }
    }

    // Phase 3: bias + SCReLU + dot with W_out.
    const float4 bias = ((const float4*)b_ft)[t];
    const float4 wo_s = ((const float4*)W_out)[t];
    const float4 wo_n = ((const float4*)(W_out + FT))[t];
    const float bb[4] = {bias.x, bias.y, bias.z, bias.w};
    const float ws[4] = {wo_s.x, wo_s.y, wo_s.z, wo_s.w};
    const float wn[4] = {wo_n.x, wo_n.y, wo_n.z, wo_n.w};
    float partial = 0.f;
    #pragma unroll
    for (int c = 0; c < 4; ++c) {
        float hs = acc[0][c] + bb[c];
        hs = fminf(fmaxf(hs, 0.f), 1.f); hs *= hs;
        float hn = acc[1][c] + bb[c];
        hn = fminf(fmaxf(hn, 0.f), 1.f); hn *= hn;
        partial = fmaf(hs, ws[c], partial);
        partial = fmaf(hn, wn[c], partial);
    }

    // Block reduction: wave64 shuffle tree, then LDS across the 4 waves.
    #pragma unroll
    for (int s = 32; s > 0; s >>= 1) partial += __shfl_down(partial, s, 64);
    const int wave = t >> 6;
    if ((t & 63) == 0) red[wave] = partial;
    __syncthreads();
    if (t == 0) {
        float x = red[0] + red[1] + red[2] + red[3] + b_out[0];
        out[b] = 1.0f / (1.0f + expf(-x));
    }
}

extern "C" void kernel_launch(void* const* d_in, const int* in_sizes, int n_in,
                              void* d_out, int out_size, void* d_ws, size_t ws_size,
                              hipStream_t stream) {
    const float* board_stm  = (const float*)d_in[0];
    const float* board_nstm = (const float*)d_in[1];
    const float* W_ft       = (const float*)d_in[2];
    const float* b_ft       = (const float*)d_in[3];
    const float* W_out      = (const float*)d_in[4];
    const float* b_out      = (const float*)d_in[5];
    float* out = (float*)d_out;

    unsigned short* Wt = (unsigned short*)d_ws;  // NF*FT bf16 = 1.5 MB

    prep_wt<<<(NF * FT + 255) / 256, 256, 0, stream>>>(W_ft, Wt);
    nnue_fwd<<<BATCH, 256, 0, stream>>>(board_stm, board_nstm, Wt, b_ft,
                                        W_out, b_out, out);
}

// Round 2
// 117.433 us; speedup vs baseline: 1.1918x; 1.1918x over previous
//
#include <hip/hip_runtime.h>
#include <hip/hip_bf16.h>
#include <stdint.h>

#define BATCH 16384
#define NF 768
#define FT 1024
#define PAD_M 4
#define DUMMY NF  // index of the zeroed row in Wt

typedef float f32x2 __attribute__((ext_vector_type(2)));

__device__ __forceinline__ float u2f(uint32_t u) {
    union { uint32_t i; float f; } x; x.i = u; return x.f;
}

// Kernel 1: W_ft [FT, NF] fp32 -> Wt [(NF+1), FT] bf16 transposed; row NF = zeros.
__global__ __launch_bounds__(256) void prep_wt(const float* __restrict__ W_ft,
                                               unsigned short* __restrict__ Wt) {
    int n = blockIdx.x * 256 + threadIdx.x;
    if (n >= (NF + 1) * FT) return;
    int o = n & (FT - 1);
    int f = n >> 10;
    float w = (f < NF) ? W_ft[(size_t)o * NF + f] : 0.0f;
    __hip_bfloat16 h = __float2bfloat16(w);
    Wt[n] = *reinterpret_cast<unsigned short*>(&h);
}

// Kernel 2: fused sparse FT + SCReLU + output layer + sigmoid.
// One block per batch row. Threads 0-127: stm outputs (8 each); 128-255: nstm.
__global__ __launch_bounds__(256) void nnue_fwd(
    const float* __restrict__ bstm, const float* __restrict__ bnstm,
    const unsigned short* __restrict__ Wt, const float* __restrict__ b_ft,
    const float* __restrict__ W_out, const float* __restrict__ b_out,
    float* __restrict__ out)
{
    const int b = blockIdx.x;
    const int t = threadIdx.x;
    const int wave = t >> 6;
    const int lane = t & 63;

    __shared__ int fidx[2][NF + PAD_M];
    __shared__ int cnt[2];
    __shared__ float red[4];

    // Phase 1: wave 0 compacts stm nonzeros, wave 1 compacts nstm.
    // Ballot-prefix: deterministic, ordered, no atomics. Boards are binary,
    // so only indices are needed (value is always 1.0).
    if (wave < 2) {
        const float* board = (wave == 0 ? bstm : bnstm) + (size_t)b * NF;
        int base = 0;
        #pragma unroll
        for (int c = 0; c < 3; ++c) {
            const float4 v = ((const float4*)board)[lane * 3 + c];
            const float arr[4] = {v.x, v.y, v.z, v.w};
            #pragma unroll
            for (int j = 0; j < 4; ++j) {
                const bool nz = (arr[j] != 0.0f);
                const uint64_t m = __ballot(nz);
                if (nz) {
                    int pos = base + __popcll(m & ((1ull << lane) - 1ull));
                    fidx[wave][pos] = lane * 12 + c * 4 + j;
                }
                base += __popcll(m);
            }
        }
        // pad trip count to a multiple of PAD_M with the zero-row index
        const int padded = (base + PAD_M - 1) & ~(PAD_M - 1);
        if (lane < padded - base) fidx[wave][base + lane] = DUMMY;
        if (lane == 0) cnt[wave] = padded;
    }
    __syncthreads();

    // Phase 2: accumulate active rows. Each thread owns 8 outputs of one
    // perspective; 16 B coalesced loads; bf16 pair -> f32 pair via shift/mask.
    const int p = t >> 7;
    const int obase = (t & 127) * 8;
    const unsigned short* wrow = Wt + obase;
    f32x2 acc[4] = {{0.f,0.f},{0.f,0.f},{0.f,0.f},{0.f,0.f}};
    const int n = cnt[p];
    #pragma unroll 4
    for (int i = 0; i < n; ++i) {
        const int f = __builtin_amdgcn_readfirstlane(fidx[p][i]);
        const uint4 w = *(const uint4*)(wrow + (size_t)f * FT);
        const uint32_t ww[4] = {w.x, w.y, w.z, w.w};
        #pragma unroll
        for (int k = 0; k < 4; ++k) {
            f32x2 q = { u2f(ww[k] << 16), u2f(ww[k] & 0xFFFF0000u) };
            acc[k] += q;
        }
    }

    // Phase 3: bias + SCReLU + dot with W_out slice.
    const float4 bias0 = *(const float4*)(b_ft + obase);
    const float4 bias1 = *(const float4*)(b_ft + obase + 4);
    const float4 wo0 = *(const float4*)(W_out + p * FT + obase);
    const float4 wo1 = *(const float4*)(W_out + p * FT + obase + 4);
    const float bb[8] = {bias0.x, bias0.y, bias0.z, bias0.w,
                         bias1.x, bias1.y, bias1.z, bias1.w};
    const float wo[8] = {wo0.x, wo0.y, wo0.z, wo0.w,
                         wo1.x, wo1.y, wo1.z, wo1.w};
    float partial = 0.0f;
    #pragma unroll
    for (int k = 0; k < 4; ++k) {
        #pragma unroll
        for (int j = 0; j < 2; ++j) {
            float h = acc[k][j] + bb[2 * k + j];
            h = fminf(fmaxf(h, 0.0f), 1.0f);
            partial = fmaf(h * h, wo[2 * k + j], partial);
        }
    }

    // Block reduction: wave shuffle tree + LDS across 4 waves.
    #pragma unroll
    for (int s = 32; s > 0; s >>= 1) partial += __shfl_down(partial, s, 64);
    if (lane == 0) red[wave] = partial;
    __syncthreads();
    if (t == 0) {
        float x = red[0] + red[1] + red[2] + red[3] + b_out[0];
        out[b] = 1.0f / (1.0f + expf(-x));
    }
}

extern "C" void kernel_launch(void* const* d_in, const int* in_sizes, int n_in,
                              void* d_out, int out_size, void* d_ws, size_t ws_size,
                              hipStream_t stream) {
    const float* board_stm  = (const float*)d_in[0];
    const float* board_nstm = (const float*)d_in[1];
    const float* W_ft       = (const float*)d_in[2];
    const float* b_ft       = (const float*)d_in[3];
    const float* W_out      = (const float*)d_in[4];
    const float* b_out      = (const float*)d_in[5];
    float* out = (float*)d_out;

    unsigned short* Wt = (unsigned short*)d_ws;  // (NF+1)*FT bf16 ≈ 1.54 MB

    prep_wt<<<((NF + 1) * FT + 255) / 256, 256, 0, stream>>>(W_ft, Wt);
    nnue_fwd<<<BATCH, 256, 0, stream>>>(board_stm, board_nstm, Wt, b_ft,
                                        W_out, b_out, out);
}